// Round 7
// baseline (238.923 us; speedup 1.0000x reference)
//
#include <hip/hip_runtime.h>

#define H    112
#define W    112
#define HW   12544
#define CIN  64
#define COUT 128
#define BATCH 8
#define KK   9
#define OFFC 18
#define EPS  1e-5f
#define TP   32      // pixels per deform block
#define KDIM 576     // CIN*KK
#define KHALF 288    // K split in two passes
#define KPAD2 296    // samp row stride (elements): 148 words % 32 = 20 -> 2-way max
#define NB   3136    // deform grid size (HW/TP * BATCH)

typedef unsigned short ushort;
typedef unsigned int uint;
typedef _Float16 half2v __attribute__((ext_vector_type(2)));
typedef _Float16 half8  __attribute__((ext_vector_type(8)));
typedef __attribute__((ext_vector_type(4))) float floatx4;

__device__ __forceinline__ half2v u2h(uint u) {
  union { uint u; half2v h; } c; c.u = u; return c.h;
}
__device__ __forceinline__ uint h2u(half2v h) {
  union { uint u; half2v h; } c; c.h = h; return c.u;
}
__device__ __forceinline__ uint pack_h2(float a, float b) {
  half2v h; h[0] = (_Float16)a; h[1] = (_Float16)b; return h2u(h);
}
__device__ __forceinline__ ushort f2h_bits(float v) {
  union { _Float16 h; ushort u; } c; c.h = (_Float16)v; return c.u;
}

// ---------------- K0: transpose x [B][CIN][HW] -> xTh [B][HW][CIN] f16 ----------------
__global__ __launch_bounds__(256) void k_transpose_x(
    const float* __restrict__ x, ushort* __restrict__ xTh) {
  __shared__ float tile[64][65];
  int b = blockIdx.y;
  int p0 = blockIdx.x * 64;
  int tid = threadIdx.x;
  int j = tid & 63, cb = tid >> 6;
#pragma unroll
  for (int i = 0; i < 16; ++i) {
    int ci = cb * 16 + i;
    tile[ci][j] = x[((size_t)(b * CIN + ci)) * HW + p0 + j];
  }
  __syncthreads();
  int px = tid >> 2, ciq = tid & 3;
#pragma unroll
  for (int g = 0; g < 4; ++g) {
    int ci = ciq * 16 + g * 4;
    uint lo = pack_h2(tile[ci + 0][px], tile[ci + 1][px]);
    uint hi = pack_h2(tile[ci + 2][px], tile[ci + 3][px]);
    *(uint2*)&xTh[((size_t)b * HW + p0 + px) * 64 + ci] = make_uint2(lo, hi);
  }
}

// ---------------- weight prep (f16) ----------------
// w_offT[oc][k], k = kk*64+ci, oc padded to 32 (zeros) -- MFMA A for offset conv
// w_mf[co][h*288 + kk*32 + cil], ci = h*32+cil          -- MFMA A for deform
__global__ __launch_bounds__(256) void k_prep_w(
    const float* __restrict__ w_off, const float* __restrict__ w_dcn,
    ushort* __restrict__ w_offT, ushort* __restrict__ w_mf) {
  int i = blockIdx.x * 256 + threadIdx.x;
  if (i < 32 * KDIM) {
    int oc = i / KDIM, k = i - oc * KDIM;
    int kk = k >> 6, ci = k & 63;
    float v = (oc < OFFC) ? w_off[(oc * CIN + ci) * KK + kk] : 0.f;
    w_offT[i] = f2h_bits(v);
  } else if (i < 32 * KDIM + COUT * KDIM) {
    int jj = i - 32 * KDIM;
    int co = jj / KDIM, k = jj - co * KDIM;
    int h = k / KHALF, r = k - h * KHALF;
    int kk = r >> 5, cil = r & 31;
    int ci = h * 32 + cil;
    w_mf[jj] = f2h_bits(w_dcn[(co * CIN + ci) * KK + kk]);
  }
}

// ---------------- K1: offset conv as register-resident f16 MFMA ----------------
__global__ __launch_bounds__(256) void k_offset_conv(
    const ushort* __restrict__ xTh, const ushort* __restrict__ w_offT,
    const float* __restrict__ bias, float* __restrict__ out) {
  int b = blockIdx.y;
  int wave = threadIdx.x >> 6, lane = threadIdx.x & 63;
  int row16 = lane & 15, quad = lane >> 4;
  int p = blockIdx.x * 64 + wave * 16 + row16;
  int ho = p / W, wo = p - ho * W;
  const ushort* xb = xTh + (size_t)b * HW * 64;

  half8 Bf[18];
#pragma unroll
  for (int ks = 0; ks < 18; ++ks) {
    int kk = ks >> 1;
    int ci0 = (ks & 1) * 32 + quad * 8;
    int kh = kk / 3, kw = kk - kh * 3;
    int yy = ho + kh - 1, xx = wo + kw - 1;
    bool valid = (yy >= 0) & (yy < H) & (xx >= 0) & (xx < W);
    half8 v = {0, 0, 0, 0, 0, 0, 0, 0};
    if (valid) v = *(const half8*)(xb + ((size_t)(yy * W + xx) << 6) + ci0);
    Bf[ks] = v;
  }
  floatx4 acc0 = {0.f, 0.f, 0.f, 0.f}, acc1 = acc0;
  const ushort* wa0 = w_offT + row16 * KDIM + quad * 8;
  const ushort* wa1 = w_offT + (16 + row16) * KDIM + quad * 8;
#pragma unroll
  for (int ks = 0; ks < 18; ++ks) {
    half8 A0 = *(const half8*)(wa0 + ks * 32);
    half8 A1 = *(const half8*)(wa1 + ks * 32);
    acc0 = __builtin_amdgcn_mfma_f32_16x16x32_f16(A0, Bf[ks], acc0, 0, 0, 0);
    acc1 = __builtin_amdgcn_mfma_f32_16x16x32_f16(A1, Bf[ks], acc1, 0, 0, 0);
  }
  float* ob = out + (size_t)b * OFFC * HW;
#pragma unroll
  for (int reg = 0; reg < 4; ++reg) {
    int oc = quad * 4 + reg;
    ob[(size_t)oc * HW + p] = acc0[reg] + bias[oc];
    int oc1 = 16 + oc;
    if (oc1 < OFFC) ob[(size_t)oc1 * HW + p] = acc1[reg] + bias[oc1];
  }
}

// ---------------- K3: deform conv (K-split f16 MFMA) -> y fp32 + per-block BN partials ----------------
__global__ __launch_bounds__(256) void k_deform(
    const ushort* __restrict__ xTh, const float* __restrict__ off,
    const ushort* __restrict__ w_mf, float* __restrict__ y,
    float* __restrict__ psT) {
  __shared__ uint4  s_wh[KK][TP];   // 4x half2 bilinear weights (duplicated pairs)
  __shared__ int4   s_i[KK][TP];    // 4 corner element offsets (px*64)
  __shared__ ushort samp[TP][KPAD2];

  int b = blockIdx.y;
  int p0 = blockIdx.x * TP;
  int bid = blockIdx.y * gridDim.x + blockIdx.x;
  int tid = threadIdx.x;
  const ushort* xb = xTh + (size_t)b * HW * 64;

  // ---- Phase A: bilinear metadata (288 tasks) ----
  for (int it = tid; it < KK * TP; it += 256) {
    int kk = it >> 5;
    int px = it & 31;
    int p = p0 + px;
    int ho = p / W, wo = p - ho * W;
    float dy = off[((size_t)b * OFFC + 2 * kk) * HW + p];
    float dx = off[((size_t)b * OFFC + 2 * kk + 1) * HW + p];
    float py = dy + (float)(ho - 1 + kk / 3);
    float pxx = dx + (float)(wo - 1 + kk % 3);
    float y0f = floorf(py), x0f = floorf(pxx);
    float wy1 = py - y0f, wx1 = pxx - x0f;
    int y0 = (int)y0f, x0 = (int)x0f;
    int y1 = y0 + 1, x1 = x0 + 1;
    float vy0 = (y0 >= 0 && y0 < H) ? 1.f : 0.f;
    float vy1 = (y1 >= 0 && y1 < H) ? 1.f : 0.f;
    float vx0 = (x0 >= 0 && x0 < W) ? 1.f : 0.f;
    float vx1 = (x1 >= 0 && x1 < W) ? 1.f : 0.f;
    int cy0 = min(max(y0, 0), H - 1), cy1 = min(max(y1, 0), H - 1);
    int cx0 = min(max(x0, 0), W - 1), cx1 = min(max(x1, 0), W - 1);
    float w00 = (1.f - wy1) * (1.f - wx1) * vy0 * vx0;
    float w01 = (1.f - wy1) * wx1 * vy0 * vx1;
    float w10 = wy1 * (1.f - wx1) * vy1 * vx0;
    float w11 = wy1 * wx1 * vy1 * vx1;
    s_wh[kk][px] = make_uint4(pack_h2(w00, w00), pack_h2(w01, w01),
                              pack_h2(w10, w10), pack_h2(w11, w11));
    s_i[kk][px] = make_int4((cy0 * W + cx0) << 6, (cy0 * W + cx1) << 6,
                            (cy1 * W + cx0) << 6, (cy1 * W + cx1) << 6);
  }
  __syncthreads();

  int wave = tid >> 6, lane = tid & 63;
  int row16 = lane & 15, quad = lane >> 4;
  int koff = quad * 8;
  int co_base = wave * 32;
  const ushort* wa0 = w_mf + (size_t)(co_base + row16) * KDIM + koff;
  const ushort* wa1 = w_mf + (size_t)(co_base + 16 + row16) * KDIM + koff;

  floatx4 acc00 = {0.f, 0.f, 0.f, 0.f}, acc01 = acc00, acc10 = acc00, acc11 = acc00;

  for (int h = 0; h < 2; ++h) {
    // ---- gather half h: 1152 tasks = 32px x 9kk x 4cig (8 ch each, packed f16) ----
#pragma unroll
    for (int r = 0; r < 5; ++r) {
      int it = tid + r * 256;
      if (it < 1152) {
        int px = it / 36;
        int rem = it - px * 36;
        int kk = rem >> 2;
        int cig = rem & 3;
        int cil0 = cig * 8;
        int cio = h * 32 + cil0;
        uint4 wh = s_wh[kk][px];
        int4 iv = s_i[kk][px];
        half2v w0 = u2h(wh.x), w1 = u2h(wh.y), w2 = u2h(wh.z), w3 = u2h(wh.w);
        uint4 c0 = *(const uint4*)(xb + iv.x + cio);
        uint4 c1 = *(const uint4*)(xb + iv.y + cio);
        uint4 c2 = *(const uint4*)(xb + iv.z + cio);
        uint4 c3 = *(const uint4*)(xb + iv.w + cio);
        uint4 res;
        res.x = h2u(w0 * u2h(c0.x) + w1 * u2h(c1.x) + w2 * u2h(c2.x) + w3 * u2h(c3.x));
        res.y = h2u(w0 * u2h(c0.y) + w1 * u2h(c1.y) + w2 * u2h(c2.y) + w3 * u2h(c3.y));
        res.z = h2u(w0 * u2h(c0.z) + w1 * u2h(c1.z) + w2 * u2h(c2.z) + w3 * u2h(c3.z));
        res.w = h2u(w0 * u2h(c0.w) + w1 * u2h(c1.w) + w2 * u2h(c2.w) + w3 * u2h(c3.w));
        *(uint4*)&samp[px][kk * 32 + cil0] = res;
      }
    }
    __syncthreads();

    // ---- MFMA over this K-half: 9 ks steps x 4 MFMA ----
    const ushort* sb0 = &samp[row16][koff];
    const ushort* sb1 = &samp[16 + row16][koff];
    const ushort* a0 = wa0 + h * KHALF;
    const ushort* a1 = wa1 + h * KHALF;
#pragma unroll
    for (int ks = 0; ks < 9; ++ks) {
      half8 A0 = *(const half8*)(a0 + ks * 32);
      half8 A1 = *(const half8*)(a1 + ks * 32);
      half8 B0 = *(const half8*)(sb0 + ks * 32);
      half8 B1 = *(const half8*)(sb1 + ks * 32);
      acc00 = __builtin_amdgcn_mfma_f32_16x16x32_f16(A0, B0, acc00, 0, 0, 0);
      acc01 = __builtin_amdgcn_mfma_f32_16x16x32_f16(A0, B1, acc01, 0, 0, 0);
      acc10 = __builtin_amdgcn_mfma_f32_16x16x32_f16(A1, B0, acc10, 0, 0, 0);
      acc11 = __builtin_amdgcn_mfma_f32_16x16x32_f16(A1, B1, acc11, 0, 0, 0);
    }
    if (h == 0) __syncthreads();
  }

  // ---- epilogue: y store (fp32, full-line) + per-block BN partials (no atomics) ----
  float* yb = y + (size_t)b * COUT * HW + p0;
#pragma unroll
  for (int reg = 0; reg < 4; ++reg) {
    int r0 = quad * 4 + reg;
    yb[(size_t)(co_base + r0) * HW + row16]      = acc00[reg];
    yb[(size_t)(co_base + r0) * HW + 16 + row16] = acc01[reg];
    yb[(size_t)(co_base + 16 + r0) * HW + row16]      = acc10[reg];
    yb[(size_t)(co_base + 16 + r0) * HW + 16 + row16] = acc11[reg];
  }
#pragma unroll
  for (int reg = 0; reg < 4; ++reg) {
    float s0 = acc00[reg] + acc01[reg];
    float q0 = acc00[reg] * acc00[reg] + acc01[reg] * acc01[reg];
    float s1 = acc10[reg] + acc11[reg];
    float q1 = acc10[reg] * acc10[reg] + acc11[reg] * acc11[reg];
#pragma unroll
    for (int m = 1; m < 16; m <<= 1) {
      s0 += __shfl_xor(s0, m, 64);
      q0 += __shfl_xor(q0, m, 64);
      s1 += __shfl_xor(s1, m, 64);
      q1 += __shfl_xor(q1, m, 64);
    }
    if (row16 == 0) {
      int c0 = co_base + quad * 4 + reg;
      int c1 = c0 + 16;
      psT[(size_t)c0 * NB + bid]         = s0;
      psT[(size_t)(128 + c0) * NB + bid] = q0;
      psT[(size_t)c1 * NB + bid]         = s1;
      psT[(size_t)(128 + c1) * NB + bid] = q1;
    }
  }
}

// ---------------- K4: reduce per-block partials -> stats[256] ----------------
__global__ __launch_bounds__(256) void k_reduce(const float* __restrict__ psT,
                                                float* __restrict__ stats) {
  int j = blockIdx.x;      // 0..255: 0..127 sums, 128..255 sumsq
  int tid = threadIdx.x;
  float s = 0.f;
  for (int i = tid; i < NB; i += 256) s += psT[(size_t)j * NB + i];
#pragma unroll
  for (int o = 32; o > 0; o >>= 1) s += __shfl_down(s, o, 64);
  __shared__ float ls[4];
  int lane = tid & 63, wid = tid >> 6;
  if (lane == 0) ls[wid] = s;
  __syncthreads();
  if (tid == 0) stats[j] = ls[0] + ls[1] + ls[2] + ls[3];
}

// ---------------- K5: finalize stats + normalize + ReLU ----------------
__global__ __launch_bounds__(256) void k_norm(const float* __restrict__ y,
                                              const float* __restrict__ stats,
                                              const float* __restrict__ gamma,
                                              const float* __restrict__ beta,
                                              float* __restrict__ out) {
  int i4 = blockIdx.x * 256 + threadIdx.x;
  const int total4 = BATCH * COUT * HW / 4;
  if (i4 >= total4) return;
  size_t i = (size_t)i4 * 4;
  int c = (int)((i / HW) & (COUT - 1));
  const float N = (float)(BATCH * HW);
  float m = stats[c] / N;
  float var = stats[COUT + c] / N - m * m;
  float r = rsqrtf(var + EPS);
  float g = gamma[c], bt = beta[c];
  float4 v = *(const float4*)&y[i];
  v.x = fmaxf(0.f, (v.x - m) * r * g + bt);
  v.y = fmaxf(0.f, (v.y - m) * r * g + bt);
  v.z = fmaxf(0.f, (v.z - m) * r * g + bt);
  v.w = fmaxf(0.f, (v.w - m) * r * g + bt);
  *(float4*)&out[i] = v;
}

extern "C" void kernel_launch(void* const* d_in, const int* in_sizes, int n_in,
                              void* d_out, int out_size, void* d_ws, size_t ws_size,
                              hipStream_t stream) {
  const float* x     = (const float*)d_in[0];
  const float* w_off = (const float*)d_in[1];
  const float* b_off = (const float*)d_in[2];
  const float* w_dcn = (const float*)d_in[3];
  // d_in[4] = b_dcn: cancels exactly through batch-norm
  const float* gamma = (const float*)d_in[5];
  const float* beta  = (const float*)d_in[6];
  float* out = (float*)d_out;

  float* ws = (float*)d_ws;
  float*  off_buf = ws;                               //  1,806,336 floats
  float*  psT     = off_buf + 1806336;                //    802,816 floats
  float*  stats   = psT + 802816;                     //        256
  float*  y       = stats + 256;                      // 12,845,056 floats
  ushort* xTh     = (ushort*)(y + 12845056);          //  6,422,528 ushorts
  ushort* w_mf    = xTh + 6422528;                    //     73,728
  ushort* w_offT  = w_mf + 73728;                     //     18,432
  // total ~75 MB

  k_transpose_x<<<dim3(HW / 64, BATCH), 256, 0, stream>>>(x, xTh);
  k_prep_w<<<(32 * KDIM + COUT * KDIM + 255) / 256, 256, 0, stream>>>(w_off, w_dcn, w_offT, w_mf);
  k_offset_conv<<<dim3(HW / 64, BATCH), 256, 0, stream>>>(xTh, w_offT, b_off, off_buf);
  k_deform<<<dim3(HW / TP, BATCH), 256, 0, stream>>>(xTh, off_buf, w_mf, y, psT);
  k_reduce<<<256, 256, 0, stream>>>(psT, stats);
  k_norm<<<(BATCH * COUT * HW / 4 + 255) / 256, 256, 0, stream>>>(y, stats, gamma, beta, out);
}